// Round 4
// baseline (1344.336 us; speedup 1.0000x reference)
//
#include <hip/hip_runtime.h>

#define B_ 8
#define M_ 4096
#define W_ 128
#define C_ 32
#define NN_ 16
#define NBLK 1024

typedef short s16x8 __attribute__((ext_vector_type(8)));
typedef float f32x4 __attribute__((ext_vector_type(4)));

static __device__ __forceinline__ unsigned short f2bf(float f) {
  unsigned u = __builtin_bit_cast(unsigned, f);
  u = u + 0x7FFFu + ((u >> 16) & 1u);   // RNE
  return (unsigned short)(u >> 16);
}
static __device__ __forceinline__ s16x8 cvt8v(float4 a, float4 b) {
  s16x8 r;
  r[0] = (short)f2bf(a.x); r[1] = (short)f2bf(a.y);
  r[2] = (short)f2bf(a.z); r[3] = (short)f2bf(a.w);
  r[4] = (short)f2bf(b.x); r[5] = (short)f2bf(b.y);
  r[6] = (short)f2bf(b.z); r[7] = (short)f2bf(b.w);
  return r;
}
static __device__ __forceinline__ float safeexp(float a) {
  return expf(fminf(a, 87.f));
}

// ---------------------------------------------------------------- poison (diagnostic sentinel)
__global__ void poison_kernel(float* __restrict__ out, int n, float val) {
  int t = blockIdx.x * blockDim.x + threadIdx.x;
  if (t < n) out[t] = val;
}

// ---------------------------------------------------------------- software grid barrier
// Same mechanism ROCm uses for grid.sync(): global arrive-counter + generation
// flag, agent-scope atomics. __threadfence() = agent release/acquire -> L2
// writeback/invalidate (cross-XCD visibility, G16). Bounded spin: a residency
// failure produces a wrong answer (test fails) instead of a hang.
static __device__ __forceinline__ void gridbar(unsigned* __restrict__ bar, int tid) {
  __syncthreads();
  if (tid == 0) {
    unsigned* cnt = bar;
    unsigned* gen = bar + 64;                  // separate cacheline
    unsigned g = __hip_atomic_load(gen, __ATOMIC_RELAXED, __HIP_MEMORY_SCOPE_AGENT);
    __threadfence();                           // release this block's stores
    unsigned old = __hip_atomic_fetch_add(cnt, 1u, __ATOMIC_ACQ_REL,
                                          __HIP_MEMORY_SCOPE_AGENT);
    if (old == NBLK - 1) {
      __hip_atomic_store(cnt, 0u, __ATOMIC_RELAXED, __HIP_MEMORY_SCOPE_AGENT);
      __hip_atomic_fetch_add(gen, 1u, __ATOMIC_RELEASE, __HIP_MEMORY_SCOPE_AGENT);
    } else {
      int t = 0;
      while (__hip_atomic_load(gen, __ATOMIC_ACQUIRE,
                               __HIP_MEMORY_SCOPE_AGENT) == g) {
        __builtin_amdgcn_s_sleep(4);
        if (++t > (1 << 18)) break;            // safety valve
      }
    }
    __threadfence();                           // acquire other blocks' stores
  }
  __syncthreads();
}

// ================================================================ device bodies

// ---- attention row (proven)
static __device__ void attn_row(
    int m, const float* __restrict__ pseudo, const int* __restrict__ Lidx,
    const float* __restrict__ edge_w, const float* __restrict__ edge_b,
    const float* __restrict__ mu0, const float* __restrict__ sg0,
    const float* __restrict__ mu1, const float* __restrict__ sg1,
    float* __restrict__ we0, float* __restrict__ we1, int* __restrict__ colb) {
  float w0[NN_], w1[NN_];
  int col[NN_];
#pragma unroll
  for (int n = 0; n < NN_; n++) {
    int e = m * NN_ + n;
    float p0 = pseudo[e * 2], p1 = pseudo[e * 2 + 1];
    float emb[5];
#pragma unroll
    for (int d = 0; d < 5; d++)
      emb[d] = p0 * edge_w[d * 2] + p1 * edge_w[d * 2 + 1] + edge_b[d];
    float a0 = 0.f, a1 = 0.f;
#pragma unroll
    for (int j = 0; j < 4; j++) {
      float qa = 0.f, qb = 0.f;
#pragma unroll
      for (int d = 0; d < 5; d++) {
        float u0 = emb[d] - mu0[j * 5 + d];
        qa += u0 * u0 * sg0[j * 5 + d];
        float u1 = emb[d] - mu1[j * 5 + d];
        qb += u1 * u1 * sg1[j * 5 + d];
      }
      a0 += safeexp(-0.5f * qa);
      a1 += safeexp(-0.5f * qb);
    }
    w0[n] = a0; w1[n] = a1;
    col[n] = Lidx[e] % M_;
  }
  float mx0 = w0[0], mx1 = w1[0];
#pragma unroll
  for (int n = 1; n < NN_; n++) { mx0 = fmaxf(mx0, w0[n]); mx1 = fmaxf(mx1, w1[n]); }
  float s0 = 0.f, s1 = 0.f;
#pragma unroll
  for (int n = 0; n < NN_; n++) {
    w0[n] = safeexp(w0[n] - mx0); s0 += w0[n];
    w1[n] = safeexp(w1[n] - mx1); s1 += w1[n];
  }
  float r0 = 1.f / s0, r1 = 1.f / s1;
#pragma unroll
  for (int n = 0; n < NN_; n++) {
    bool last = true;                       // numpy fancy-set: last duplicate wins
#pragma unroll
    for (int n2 = n + 1; n2 < NN_; n2++)
      if (col[n2] == col[n]) last = false;
    int e = m * NN_ + n;
    we0[e] = last ? w0[n] * r0 : 0.f;
    we1[e] = last ? w1[n] * r1 : 0.f;
    colb[e] = col[n];
  }
}

// ---- proj0 tile: G[r][0:32]=x@l1w0.T, G[r][32:64]=x@l2w0.T
static __device__ void proj0_tile(
    int blk, int tid, const float* __restrict__ x, const float* __restrict__ l1w0,
    const float* __restrict__ l2w0, float* __restrict__ G) {
  int lane = tid & 63, wave = tid >> 6;
  int l16 = lane & 15, quad = lane >> 4;
  int tile = blk * 4 + wave;                   // 2048 tiles of 16 rows
  f32x4 acc[4];
#pragma unroll
  for (int ct = 0; ct < 4; ct++) acc[ct] = (f32x4){0.f, 0.f, 0.f, 0.f};
  int row = tile * 16 + l16;
  const float* xr = x + (size_t)row * 128 + quad * 8;
#pragma unroll
  for (int kit = 0; kit < 4; kit++) {
    const float* ap = xr + kit * 32;
    s16x8 a = cvt8v(*(const float4*)ap, *(const float4*)(ap + 4));
#pragma unroll
    for (int ct = 0; ct < 4; ct++) {
      int out = ct * 16 + l16;
      const float* src = (out < 32 ? l1w0 + out * 128 : l2w0 + (out - 32) * 128)
                         + kit * 32 + quad * 8;
      s16x8 bf = cvt8v(*(const float4*)src, *(const float4*)(src + 4));
      acc[ct] = __builtin_amdgcn_mfma_f32_16x16x32_bf16(a, bf, acc[ct], 0, 0, 0);
    }
  }
  int rbase = tile * 16 + quad * 4;            // C/D: col=lane&15, row=quad*4+i (m89)
#pragma unroll
  for (int ct = 0; ct < 4; ct++)
#pragma unroll
    for (int i = 0; i < 4; i++)
      G[(size_t)(rbase + i) * 64 + ct * 16 + l16] = acc[ct][i];
}

// ---- conv block (proven): h = L.G1 + G2 + b1 + b2; BN partials. smem: 1280 B.
static __device__ void conv_block(
    int cb, int tid, char* smem,
    const float* __restrict__ G, const float* __restrict__ we,
    const int* __restrict__ colb, const float* __restrict__ b1c,
    const float* __restrict__ b2c, float* __restrict__ h,
    float* __restrict__ bns, float* __restrict__ bnq) {
  float (*s_we)[16] = (float(*)[16])smem;
  int   (*s_cn)[16] = (int(*)[16])(smem + 512);
  float* s_s = (float*)(smem + 1024);
  float* s_q = (float*)(smem + 1152);
  if (tid < 128) {
    int row = tid >> 4, nn = tid & 15;
    int m = (cb * 8 + row) & 4095;             // attn arrays are per-m
    s_we[row][nn] = we[m * 16 + nn];
    s_cn[row][nn] = colb[m * 16 + nn];
  } else if (tid < 160) {
    s_s[tid - 128] = 0.f;
    s_q[tid - 128] = 0.f;
  }
  __syncthreads();
  int row = tid >> 5, c = tid & 31;
  int r = cb * 8 + row;
  int b = r >> 12;
  const float* Gb = G + ((size_t)b << 18);     // b*4096*64
  float acc = 0.f;
#pragma unroll
  for (int nn = 0; nn < NN_; nn++)             // 16 independent gathers in flight
    acc += s_we[row][nn] * Gb[s_cn[row][nn] * 64 + c];
  float hv = acc + G[(size_t)r * 64 + 32 + c] + b1c[c] + b2c[c];
  h[(size_t)r * 32 + c] = hv;
  atomicAdd(&s_s[c], hv);
  atomicAdd(&s_q[c], hv * hv);
  __syncthreads();
  if (tid < 32) {
    int slot = cb & 255;
    atomicAdd(&bns[tid * 256 + slot], s_s[tid]);
    atomicAdd(&bnq[tid * 256 + slot], s_q[tid]);
  }
}

// ---- BN finalize, computed LOCALLY per block into LDS s_sc[64] (scale|shift).
// Re-reduces the 64KB partial arrays (L2/L3-hot) -> removes a grid barrier
// and the single-block serialization. smem scratch: 2048 B.
static __device__ void bnfin_local(
    int tid, char* smem, const float* __restrict__ bns, const float* __restrict__ bnq,
    const float* __restrict__ g, const float* __restrict__ bb,
    float* __restrict__ s_sc) {
  float (*red)[8][32] = (float(*)[8][32])smem;
  int c = tid & 31, part = tid >> 5;
  float s = 0.f, q = 0.f;
#pragma unroll 8
  for (int i = 0; i < 32; i++) {
    s += bns[c * 256 + part * 32 + i];
    q += bnq[c * 256 + part * 32 + i];
  }
  red[0][part][c] = s;
  red[1][part][c] = q;
  __syncthreads();
  if (tid < 32) {
    float S = 0.f, Q = 0.f;
#pragma unroll
    for (int p = 0; p < 8; p++) { S += red[0][p][tid]; Q += red[1][p][tid]; }
    float mean = S * (1.f / 32768.f);
    float var = fmaxf(Q * (1.f / 32768.f) - mean * mean, 0.f);
    float sc = g[tid] * rsqrtf(var + 1e-5f);
    s_sc[tid] = sc;
    s_sc[32 + tid] = bb[tid] - mean * sc;
  }
  __syncthreads();
}

// ---- proj1 tile (K=32): a=relu(bn0(h0)); G=[a@l1w1.T | a@l2w1.T]; sc0 in LDS
static __device__ void proj1_tile(
    int blk, int tid, const float* __restrict__ h0, const float* __restrict__ sc0,
    const float* __restrict__ l1w1, const float* __restrict__ l2w1,
    float* __restrict__ G) {
  int lane = tid & 63, wave = tid >> 6;
  int l16 = lane & 15, quad = lane >> 4;
  int tile = blk * 4 + wave;
  int row = tile * 16 + l16;
  const float* hr = h0 + (size_t)row * 32 + quad * 8;
  float4 hv0 = *(const float4*)hr;
  float4 hv1 = *(const float4*)(hr + 4);
  float av[8] = {hv0.x, hv0.y, hv0.z, hv0.w, hv1.x, hv1.y, hv1.z, hv1.w};
  s16x8 a;
#pragma unroll
  for (int j = 0; j < 8; j++) {
    float scv = sc0[quad * 8 + j];
    float shv = sc0[32 + quad * 8 + j];
    a[j] = (short)f2bf(fmaxf(av[j] * scv + shv, 0.f));
  }
  f32x4 acc[4];
#pragma unroll
  for (int ct = 0; ct < 4; ct++) {
    int out = ct * 16 + l16;
    const float* src = (out < 32 ? l1w1 + out * 32 : l2w1 + (out - 32) * 32) + quad * 8;
    s16x8 bf = cvt8v(*(const float4*)src, *(const float4*)(src + 4));
    f32x4 z = {0.f, 0.f, 0.f, 0.f};
    acc[ct] = __builtin_amdgcn_mfma_f32_16x16x32_bf16(a, bf, z, 0, 0, 0);
  }
  int rbase = tile * 16 + quad * 4;
#pragma unroll
  for (int ct = 0; ct < 4; ct++)
#pragma unroll
    for (int i = 0; i < 4; i++)
      G[(size_t)(rbase + i) * 64 + ct * 16 + l16] = acc[ct][i];
}

// ---- fc1 block (MFMA, K-chunk=512 -> 16 KB LDS): u in [0,1024); sc1 in LDS
static __device__ void fc1_block(
    int u, int tid, char* smem, const float* __restrict__ h1,
    const float* __restrict__ sc1, const float* __restrict__ fc1w,
    float* __restrict__ fc1acc) {
  short* als = (short*)smem;                   // bf16 [16][512], row stride 1024 B, swizzled
  int kc = u >> 2;                             // 0..255: k-chunk of 512
  int og = u & 3;                              // 0..3: outputs og*64..+63
  size_t kbase = (size_t)kc << 9;
  for (int s = tid; s < 2048; s += 256) {      // 2048 short4 slots
    int rowb = s >> 7;                         // 0..15 (rows 8..15 stay zero)
    int k4 = (s & 127) << 2;
    short4 v4 = {0, 0, 0, 0};
    if (rowb < 8) {
      float4 hv = *(const float4*)(h1 + ((size_t)rowb << 17) + kbase + k4);
      int c = k4 & 31;
      float4 scv = *(const float4*)(sc1 + c);
      float4 shv = *(const float4*)(sc1 + 32 + c);
      v4.x = (short)f2bf(fmaxf(hv.x * scv.x + shv.x, 0.f));
      v4.y = (short)f2bf(fmaxf(hv.y * scv.y + shv.y, 0.f));
      v4.z = (short)f2bf(fmaxf(hv.z * scv.z + shv.z, 0.f));
      v4.w = (short)f2bf(fmaxf(hv.w * scv.w + shv.w, 0.f));
    }
    int byte = ((rowb << 10) + (k4 << 1)) ^ ((rowb & 7) << 4);  // G4 swizzle
    *(short4*)((char*)als + byte) = v4;
  }
  __syncthreads();
  int lane = tid & 63, wave = tid >> 6;
  int l16 = lane & 15, quad = lane >> 4;
  int o = og * 64 + wave * 16 + l16;
  const float* wr = fc1w + (size_t)o * 131072 + kbase + quad * 8;
  int abase = (l16 << 10) + (quad << 4);
  int axor = (l16 & 7) << 4;
  f32x4 acc = {0.f, 0.f, 0.f, 0.f};
#pragma unroll 4
  for (int kk = 0; kk < 16; kk++) {
    const float* wp = wr + kk * 32;
    s16x8 bfr = cvt8v(*(const float4*)wp, *(const float4*)(wp + 4));
    s16x8 afr = *(const s16x8*)((const char*)als + ((abase + (kk << 6)) ^ axor));
    acc = __builtin_amdgcn_mfma_f32_16x16x32_bf16(afr, bfr, acc, 0, 0, 0);
  }
  if (quad < 2) {                              // D rows 0..7 = batches (m89 layout)
#pragma unroll
    for (int i = 0; i < 4; i++)
      atomicAdd(&fc1acc[(quad * 4 + i) * 256 + o], acc[i]);
  }
}

// ---- fc2 element
static __device__ void fc2_elem(
    int t, const float* __restrict__ fc1acc, const float* __restrict__ fc2w,
    const float* __restrict__ fc2b, float* __restrict__ out) {
  int b = t / 53, j = t - b * 53;
  float s = fc2b[j];
  const float* fa = fc1acc + b * 256;
  const float* wr = fc2w + j * 256;
#pragma unroll 8
  for (int o = 0; o < 256; o++) s += fmaxf(fa[o], 0.f) * wr[o];
  out[t] = s;
}

// ---- L3-warm: dead-read a range of fc1w; asm keeps the loads live (rule #17)
static __device__ __forceinline__ void prefetch_range(
    const float4* __restrict__ p, int n, int idx, int stride) {
  float acc = 0.f;
  for (int i = idx; i < n; i += stride) {
    float4 v = p[i];
    acc += v.x + v.y + v.z + v.w;
  }
  asm volatile("" :: "v"(acc));
}

// ---------------------------------------------------------------- init: fc1acc, bn slots, barrier words
__global__ __launch_bounds__(256) void init_kernel(
    float* __restrict__ fc1acc, const float* __restrict__ fc1b,
    float* __restrict__ bn, unsigned* __restrict__ bar) {
  int g = blockIdx.x * 256 + threadIdx.x;
  if (g < 2048) fc1acc[g] = fc1b[g & 255];
  else if (g < 34816) bn[g - 2048] = 0.f;
  else if (g < 34944) bar[g - 34816] = 0u;
}

// ================================================================ fused kernel
// grid = 1024 x 256, __launch_bounds__(256,4) -> VGPR<=128, LDS 16.6 KB ->
// exactly 4 blocks/CU over 256 CUs: all 1024 blocks co-resident (S1 pattern).
// 5 software grid barriers replace 9 kernel boundaries. Idle blocks in P1/P3
// stream fc1w into the 256 MB L3 so P5 reads it at L3 speed.
__global__ __launch_bounds__(256, 4) void fused_kernel(
    const float* __restrict__ x, const float* __restrict__ pseudo,
    const int* __restrict__ Lidx,
    const float* __restrict__ edge_w, const float* __restrict__ edge_b,
    const float* __restrict__ mu0, const float* __restrict__ sg0,
    const float* __restrict__ mu1, const float* __restrict__ sg1,
    const float* __restrict__ l1w0, const float* __restrict__ l1b0,
    const float* __restrict__ l2w0, const float* __restrict__ l2b0,
    const float* __restrict__ l1w1, const float* __restrict__ l1b1,
    const float* __restrict__ l2w1, const float* __restrict__ l2b1,
    const float* __restrict__ bng0, const float* __restrict__ bnb0,
    const float* __restrict__ bng1, const float* __restrict__ bnb1,
    const float* __restrict__ fc1w, const float* __restrict__ fc2w,
    const float* __restrict__ fc2b,
    float* __restrict__ out,
    int* __restrict__ colb, float* __restrict__ we0, float* __restrict__ we1,
    float* __restrict__ G, float* __restrict__ h,
    float* __restrict__ bn, float* __restrict__ fc1acc,
    unsigned* __restrict__ bar) {
  __shared__ char smem[16640];
  float* s_sc = (float*)(smem + 16384);        // scale[32] | shift[32]
  int bid = blockIdx.x, tid = threadIdx.x;

  // ---- P1: proj0 (0..511) | attn (512..527) | prefetch fc1w half0 (528..1023)
  if (bid < 512) {
    proj0_tile(bid, tid, x, l1w0, l2w0, G);
  } else if (bid < 528) {
    attn_row((bid - 512) * 256 + tid, pseudo, Lidx, edge_w, edge_b,
             mu0, sg0, mu1, sg1, we0, we1, colb);
  } else {
    prefetch_range((const float4*)fc1w, 4194304, (bid - 528) * 256 + tid, 126976);
  }
  gridbar(bar, tid);

  // ---- P2: conv0 x4
  for (int it = 0; it < 4; it++) {
    __syncthreads();
    conv_block(bid + it * 1024, tid, smem, G, we0, colb, l1b0, l2b0,
               h, bn, bn + 8192);
  }
  gridbar(bar, tid);

  // ---- P3: [bnfin0-local + proj1] (0..511) | prefetch half1 (512..1023)
  if (bid < 512) {
    bnfin_local(tid, smem, bn, bn + 8192, bng0, bnb0, s_sc);
    proj1_tile(bid, tid, h, s_sc, l1w1, l2w1, G);
  } else {
    prefetch_range((const float4*)fc1w + 4194304, 4194304,
                   (bid - 512) * 256 + tid, 131072);
  }
  gridbar(bar, tid);

  // ---- P4: conv1 x4
  for (int it = 0; it < 4; it++) {
    __syncthreads();
    conv_block(bid + it * 1024, tid, smem, G, we1, colb, l1b1, l2b1,
               h, bn + 16384, bn + 24576);
  }
  gridbar(bar, tid);

  // ---- P5: bnfin1-local + fc1 (weights L3-hot)
  bnfin_local(tid, smem, bn + 16384, bn + 24576, bng1, bnb1, s_sc);
  fc1_block(bid, tid, smem, h, s_sc, fc1w, fc1acc);
  gridbar(bar, tid);

  // ---- P6: fc2
  int gtid = bid * 256 + tid;
  if (gtid < 424) fc2_elem(gtid, fc1acc, fc2w, fc2b, out);
}

// ---------------------------------------------------------------- launch
extern "C" void kernel_launch(void* const* d_in, const int* in_sizes, int n_in,
                              void* d_out, int out_size, void* d_ws, size_t ws_size,
                              hipStream_t stream) {
  float* out = (float*)d_out;
  int bad = 0;
  if (n_in != 25) bad = 2;
  else if (in_sizes[0] != 4194304) bad = 3;
  else if (in_sizes[2] != 65536) bad = 4;
  else if (in_sizes[21] != 33554432) bad = 5;
  else if (out_size != 424) bad = 6;
  else if (ws_size < 13509632) bad = 1;
  if (bad) {
    poison_kernel<<<2, 256, 0, stream>>>(out, out_size, (float)bad * 1.0e6f);
    return;
  }

  const float* x      = (const float*)d_in[0];
  const float* pseudo = (const float*)d_in[1];
  const int*   Lidx   = (const int*)d_in[2];
  const float* edge_w = (const float*)d_in[3];
  const float* edge_b = (const float*)d_in[4];
  const float* mu0    = (const float*)d_in[5];
  const float* sg0    = (const float*)d_in[6];
  const float* mu1    = (const float*)d_in[7];
  const float* sg1    = (const float*)d_in[8];
  const float* l1w0   = (const float*)d_in[9];
  const float* l1b0   = (const float*)d_in[10];
  const float* l2w0   = (const float*)d_in[11];
  const float* l2b0   = (const float*)d_in[12];
  const float* l1w1   = (const float*)d_in[13];
  const float* l1b1   = (const float*)d_in[14];
  const float* l2w1   = (const float*)d_in[15];
  const float* l2b1   = (const float*)d_in[16];
  const float* bng0   = (const float*)d_in[17];
  const float* bnb0   = (const float*)d_in[18];
  const float* bng1   = (const float*)d_in[19];
  const float* bnb1   = (const float*)d_in[20];
  const float* fc1w   = (const float*)d_in[21];
  const float* fc1b   = (const float*)d_in[22];
  const float* fc2w   = (const float*)d_in[23];
  const float* fc2b   = (const float*)d_in[24];

  char* Wp = (char*)d_ws;
  int*      colb   = (int*)     (Wp + 0);          // 65536 i32
  float*    we0    = (float*)   (Wp + 262144);     // 65536 f32
  float*    we1    = (float*)   (Wp + 524288);     // 65536 f32
  float*    G      = (float*)   (Wp + 786432);     // 32768 x 64 f32 (8 MB)
  float*    h0     = (float*)   (Wp + 9175040);    // 32768 x 32 f32 (4 MB); h1 aliases
  float*    bn     = (float*)   (Wp + 13369344);   // 4 x (32ch x 256 slots) f32
  float*    fc1acc = (float*)   (Wp + 13500928);   // 8x256 f32
  unsigned* bar    = (unsigned*)(Wp + 13509120);   // barrier: cnt @0, gen @64 (512 B)

  init_kernel<<<137, 256, 0, stream>>>(fc1acc, fc1b, bn, bar);
  fused_kernel<<<1024, 256, 0, stream>>>(
      x, pseudo, Lidx, edge_w, edge_b, mu0, sg0, mu1, sg1,
      l1w0, l1b0, l2w0, l2b0, l1w1, l1b1, l2w1, l2b1,
      bng0, bnb0, bng1, bnb1, fc1w, fc2w, fc2b, out,
      colb, we0, we1, G, h0, bn, fc1acc, bar);
}

// Round 5
// 341.359 us; speedup vs baseline: 3.9382x; 3.9382x over previous
//
#include <hip/hip_runtime.h>

#define B_ 8
#define M_ 4096
#define W_ 128
#define C_ 32
#define NN_ 16

typedef short s16x8 __attribute__((ext_vector_type(8)));
typedef float f32x4 __attribute__((ext_vector_type(4)));

static __device__ __forceinline__ unsigned short f2bf(float f) {
  unsigned u = __builtin_bit_cast(unsigned, f);
  u = u + 0x7FFFu + ((u >> 16) & 1u);   // RNE
  return (unsigned short)(u >> 16);
}
static __device__ __forceinline__ s16x8 cvt8v(float4 a, float4 b) {
  s16x8 r;
  r[0] = (short)f2bf(a.x); r[1] = (short)f2bf(a.y);
  r[2] = (short)f2bf(a.z); r[3] = (short)f2bf(a.w);
  r[4] = (short)f2bf(b.x); r[5] = (short)f2bf(b.y);
  r[6] = (short)f2bf(b.z); r[7] = (short)f2bf(b.w);
  return r;
}
static __device__ __forceinline__ float safeexp(float a) {
  return expf(fminf(a, 87.f));
}

// ---------------------------------------------------------------- poison (diagnostic sentinel)
__global__ void poison_kernel(float* __restrict__ out, int n, float val) {
  int t = blockIdx.x * blockDim.x + threadIdx.x;
  if (t < n) out[t] = val;
}

// ================================================================ device bodies (all proven)

// ---- attention row
static __device__ void attn_row(
    int m, const float* __restrict__ pseudo, const int* __restrict__ Lidx,
    const float* __restrict__ edge_w, const float* __restrict__ edge_b,
    const float* __restrict__ mu0, const float* __restrict__ sg0,
    const float* __restrict__ mu1, const float* __restrict__ sg1,
    float* __restrict__ we0, float* __restrict__ we1, int* __restrict__ colb) {
  float w0[NN_], w1[NN_];
  int col[NN_];
#pragma unroll
  for (int n = 0; n < NN_; n++) {
    int e = m * NN_ + n;
    float p0 = pseudo[e * 2], p1 = pseudo[e * 2 + 1];
    float emb[5];
#pragma unroll
    for (int d = 0; d < 5; d++)
      emb[d] = p0 * edge_w[d * 2] + p1 * edge_w[d * 2 + 1] + edge_b[d];
    float a0 = 0.f, a1 = 0.f;
#pragma unroll
    for (int j = 0; j < 4; j++) {
      float qa = 0.f, qb = 0.f;
#pragma unroll
      for (int d = 0; d < 5; d++) {
        float u0 = emb[d] - mu0[j * 5 + d];
        qa += u0 * u0 * sg0[j * 5 + d];
        float u1 = emb[d] - mu1[j * 5 + d];
        qb += u1 * u1 * sg1[j * 5 + d];
      }
      a0 += safeexp(-0.5f * qa);
      a1 += safeexp(-0.5f * qb);
    }
    w0[n] = a0; w1[n] = a1;
    col[n] = Lidx[e] % M_;
  }
  float mx0 = w0[0], mx1 = w1[0];
#pragma unroll
  for (int n = 1; n < NN_; n++) { mx0 = fmaxf(mx0, w0[n]); mx1 = fmaxf(mx1, w1[n]); }
  float s0 = 0.f, s1 = 0.f;
#pragma unroll
  for (int n = 0; n < NN_; n++) {
    w0[n] = safeexp(w0[n] - mx0); s0 += w0[n];
    w1[n] = safeexp(w1[n] - mx1); s1 += w1[n];
  }
  float r0 = 1.f / s0, r1 = 1.f / s1;
#pragma unroll
  for (int n = 0; n < NN_; n++) {
    bool last = true;                       // numpy fancy-set: last duplicate wins
#pragma unroll
    for (int n2 = n + 1; n2 < NN_; n2++)
      if (col[n2] == col[n]) last = false;
    int e = m * NN_ + n;
    we0[e] = last ? w0[n] * r0 : 0.f;
    we1[e] = last ? w1[n] * r1 : 0.f;
    colb[e] = col[n];
  }
}

// ---- proj0 tile: G[r][0:32]=x@l1w0.T, G[r][32:64]=x@l2w0.T
static __device__ void proj0_tile(
    int blk, int tid, const float* __restrict__ x, const float* __restrict__ l1w0,
    const float* __restrict__ l2w0, float* __restrict__ G) {
  int lane = tid & 63, wave = tid >> 6;
  int l16 = lane & 15, quad = lane >> 4;
  int tile = blk * 4 + wave;                   // 2048 tiles of 16 rows
  f32x4 acc[4];
#pragma unroll
  for (int ct = 0; ct < 4; ct++) acc[ct] = (f32x4){0.f, 0.f, 0.f, 0.f};
  int row = tile * 16 + l16;
  const float* xr = x + (size_t)row * 128 + quad * 8;
#pragma unroll
  for (int kit = 0; kit < 4; kit++) {
    const float* ap = xr + kit * 32;
    s16x8 a = cvt8v(*(const float4*)ap, *(const float4*)(ap + 4));
#pragma unroll
    for (int ct = 0; ct < 4; ct++) {
      int out = ct * 16 + l16;
      const float* src = (out < 32 ? l1w0 + out * 128 : l2w0 + (out - 32) * 128)
                         + kit * 32 + quad * 8;
      s16x8 bf = cvt8v(*(const float4*)src, *(const float4*)(src + 4));
      acc[ct] = __builtin_amdgcn_mfma_f32_16x16x32_bf16(a, bf, acc[ct], 0, 0, 0);
    }
  }
  int rbase = tile * 16 + quad * 4;            // C/D: col=lane&15, row=quad*4+i (m89)
#pragma unroll
  for (int ct = 0; ct < 4; ct++)
#pragma unroll
    for (int i = 0; i < 4; i++)
      G[(size_t)(rbase + i) * 64 + ct * 16 + l16] = acc[ct][i];
}

// ---- conv block: h = L.G1 + G2 + b1 + b2; BN partials. smem: 1280 B.
static __device__ void conv_block(
    int cb, int tid, char* smem,
    const float* __restrict__ G, const float* __restrict__ we,
    const int* __restrict__ colb, const float* __restrict__ b1c,
    const float* __restrict__ b2c, float* __restrict__ h,
    float* __restrict__ bns, float* __restrict__ bnq) {
  float (*s_we)[16] = (float(*)[16])smem;
  int   (*s_cn)[16] = (int(*)[16])(smem + 512);
  float* s_s = (float*)(smem + 1024);
  float* s_q = (float*)(smem + 1152);
  if (tid < 128) {
    int row = tid >> 4, nn = tid & 15;
    int m = (cb * 8 + row) & 4095;             // attn arrays are per-m
    s_we[row][nn] = we[m * 16 + nn];
    s_cn[row][nn] = colb[m * 16 + nn];
  } else if (tid < 160) {
    s_s[tid - 128] = 0.f;
    s_q[tid - 128] = 0.f;
  }
  __syncthreads();
  int row = tid >> 5, c = tid & 31;
  int r = cb * 8 + row;
  int b = r >> 12;
  const float* Gb = G + ((size_t)b << 18);     // b*4096*64
  float acc = 0.f;
#pragma unroll
  for (int nn = 0; nn < NN_; nn++)             // 16 independent gathers in flight
    acc += s_we[row][nn] * Gb[s_cn[row][nn] * 64 + c];
  float hv = acc + G[(size_t)r * 64 + 32 + c] + b1c[c] + b2c[c];
  h[(size_t)r * 32 + c] = hv;
  atomicAdd(&s_s[c], hv);
  atomicAdd(&s_q[c], hv * hv);
  __syncthreads();
  if (tid < 32) {
    int slot = cb & 255;
    atomicAdd(&bns[tid * 256 + slot], s_s[tid]);
    atomicAdd(&bnq[tid * 256 + slot], s_q[tid]);
  }
}

// ---- BN finalize, computed locally per block into LDS s_sc[64] (scale|shift).
// Re-reduces the 64 KB partial arrays (L2/L3-hot). smem scratch: 2048 B.
static __device__ void bnfin_local(
    int tid, char* smem, const float* __restrict__ bns, const float* __restrict__ bnq,
    const float* __restrict__ g, const float* __restrict__ bb,
    float* __restrict__ s_sc) {
  float (*red)[8][32] = (float(*)[8][32])smem;
  int c = tid & 31, part = tid >> 5;
  float s = 0.f, q = 0.f;
#pragma unroll 8
  for (int i = 0; i < 32; i++) {
    s += bns[c * 256 + part * 32 + i];
    q += bnq[c * 256 + part * 32 + i];
  }
  red[0][part][c] = s;
  red[1][part][c] = q;
  __syncthreads();
  if (tid < 32) {
    float S = 0.f, Q = 0.f;
#pragma unroll
    for (int p = 0; p < 8; p++) { S += red[0][p][tid]; Q += red[1][p][tid]; }
    float mean = S * (1.f / 32768.f);
    float var = fmaxf(Q * (1.f / 32768.f) - mean * mean, 0.f);
    float sc = g[tid] * rsqrtf(var + 1e-5f);
    s_sc[tid] = sc;
    s_sc[32 + tid] = bb[tid] - mean * sc;
  }
  __syncthreads();
}

// ---- proj1 tile (K=32): a=relu(bn0(h0)); G=[a@l1w1.T | a@l2w1.T]; sc0 in LDS
static __device__ void proj1_tile(
    int blk, int tid, const float* __restrict__ h0, const float* __restrict__ sc0,
    const float* __restrict__ l1w1, const float* __restrict__ l2w1,
    float* __restrict__ G) {
  int lane = tid & 63, wave = tid >> 6;
  int l16 = lane & 15, quad = lane >> 4;
  int tile = blk * 4 + wave;
  int row = tile * 16 + l16;
  const float* hr = h0 + (size_t)row * 32 + quad * 8;
  float4 hv0 = *(const float4*)hr;
  float4 hv1 = *(const float4*)(hr + 4);
  float av[8] = {hv0.x, hv0.y, hv0.z, hv0.w, hv1.x, hv1.y, hv1.z, hv1.w};
  s16x8 a;
#pragma unroll
  for (int j = 0; j < 8; j++) {
    float scv = sc0[quad * 8 + j];
    float shv = sc0[32 + quad * 8 + j];
    a[j] = (short)f2bf(fmaxf(av[j] * scv + shv, 0.f));
  }
  f32x4 acc[4];
#pragma unroll
  for (int ct = 0; ct < 4; ct++) {
    int out = ct * 16 + l16;
    const float* src = (out < 32 ? l1w1 + out * 32 : l2w1 + (out - 32) * 32) + quad * 8;
    s16x8 bf = cvt8v(*(const float4*)src, *(const float4*)(src + 4));
    f32x4 z = {0.f, 0.f, 0.f, 0.f};
    acc[ct] = __builtin_amdgcn_mfma_f32_16x16x32_bf16(a, bf, z, 0, 0, 0);
  }
  int rbase = tile * 16 + quad * 4;
#pragma unroll
  for (int ct = 0; ct < 4; ct++)
#pragma unroll
    for (int i = 0; i < 4; i++)
      G[(size_t)(rbase + i) * 64 + ct * 16 + l16] = acc[ct][i];
}

// ---- fc2 element
static __device__ void fc2_elem(
    int t, const float* __restrict__ fc1acc, const float* __restrict__ fc2w,
    const float* __restrict__ fc2b, float* __restrict__ out) {
  int b = t / 53, j = t - b * 53;
  float s = fc2b[j];
  const float* fa = fc1acc + b * 256;
  const float* wr = fc2w + j * 256;
#pragma unroll 8
  for (int o = 0; o < 256; o++) s += fmaxf(fa[o], 0.f) * wr[o];
  out[t] = s;
}

// ================================================================ kernels (6 launches)

// ---- K1: proj0 (0..511) | attn (512..527) | init fc1acc+bn (528..663)
__global__ __launch_bounds__(256) void k1_kernel(
    const float* __restrict__ x, const float* __restrict__ l1w0,
    const float* __restrict__ l2w0, float* __restrict__ G,
    const float* __restrict__ pseudo, const int* __restrict__ Lidx,
    const float* __restrict__ edge_w, const float* __restrict__ edge_b,
    const float* __restrict__ mu0, const float* __restrict__ sg0,
    const float* __restrict__ mu1, const float* __restrict__ sg1,
    float* __restrict__ we0, float* __restrict__ we1, int* __restrict__ colb,
    float* __restrict__ fc1acc, const float* __restrict__ fc1b,
    float* __restrict__ bn) {
  int bid = blockIdx.x, tid = threadIdx.x;
  if (bid < 512) {
    proj0_tile(bid, tid, x, l1w0, l2w0, G);
  } else if (bid < 528) {
    attn_row((bid - 512) * 256 + tid, pseudo, Lidx, edge_w, edge_b,
             mu0, sg0, mu1, sg1, we0, we1, colb);
  } else {
    int g = (bid - 528) * 256 + tid;           // 0..34815
    if (g < 2048) fc1acc[g] = fc1b[g & 255];
    else bn[g - 2048] = 0.f;
  }
}

// ---- K2: conv0 (proven, unchanged)
__global__ __launch_bounds__(256) void conv_kernel(
    const float* __restrict__ G,
    const float* __restrict__ we, const int* __restrict__ colb,
    const float* __restrict__ b1c, const float* __restrict__ b2c,
    float* __restrict__ h, float* __restrict__ bns, float* __restrict__ bnq) {
  __shared__ char smem[1280];
  conv_block(blockIdx.x, threadIdx.x, smem, G, we, colb, b1c, b2c, h, bns, bnq);
}

// ---- K3: bnfin0 (local) + proj1
__global__ __launch_bounds__(256) void proj1bn_kernel(
    const float* __restrict__ h0,
    const float* __restrict__ bns, const float* __restrict__ bnq,
    const float* __restrict__ g0, const float* __restrict__ b0,
    const float* __restrict__ l1w1, const float* __restrict__ l2w1,
    float* __restrict__ G) {
  __shared__ char smem[2048];
  __shared__ __align__(16) float s_sc[64];
  bnfin_local(threadIdx.x, smem, bns, bnq, g0, b0, s_sc);
  proj1_tile(blockIdx.x, threadIdx.x, h0, s_sc, l1w1, l2w1, G);
}

// ---- K4: conv1 + fc1w L3-prefetch tail (32 KB/block x 4096 = full 134 MB).
// Dead-read kept live via asm (rule #17); warms Infinity Cache for K5 while
// conv's latency-bound gather leaves HBM BW idle.
__global__ __launch_bounds__(256) void conv_pf_kernel(
    const float* __restrict__ G,
    const float* __restrict__ we, const int* __restrict__ colb,
    const float* __restrict__ b1c, const float* __restrict__ b2c,
    float* __restrict__ h, float* __restrict__ bns, float* __restrict__ bnq,
    const float* __restrict__ fc1w) {
  __shared__ char smem[1280];
  conv_block(blockIdx.x, threadIdx.x, smem, G, we, colb, b1c, b2c, h, bns, bnq);
  const float4* pw = (const float4*)fc1w;
  int base = blockIdx.x * 2048 + threadIdx.x;
  float a = 0.f;
#pragma unroll
  for (int j = 0; j < 8; j++) {
    float4 v = pw[base + j * 256];
    a += v.x + v.y + v.z + v.w;
  }
  asm volatile("" :: "v"(a));
}

// ---- K5: bnfin1 (local) + fc1 MFMA. 1024 blocks = (kc 0..127) x (og 0..7).
// Stage A-chunk [16][1024] bf16 (swizzled, round-2 proven layout); 4 waves =
// 2 output-16 groups x 2 K-halves; LDS cross-wave reduce keeps fc1acc
// contention at 128 adds/word. Weights read from L3 (warmed by K4).
__global__ __launch_bounds__(256) void fc1bn_kernel(
    const float* __restrict__ h1,
    const float* __restrict__ bns, const float* __restrict__ bnq,
    const float* __restrict__ g1, const float* __restrict__ b1,
    const float* __restrict__ fc1w, float* __restrict__ fc1acc) {
  __shared__ char smem[32768];
  __shared__ __align__(16) float s_sc[64];
  int tid = threadIdx.x;
  bnfin_local(tid, smem, bns, bnq, g1, b1, s_sc);
  short* als = (short*)smem;                   // bf16 [16][1024], row stride 2048 B
  int kc = blockIdx.x >> 3;                    // 0..127: k-chunk of 1024
  int og = blockIdx.x & 7;                     // 0..7: outputs og*32..+31
  size_t kbase = (size_t)kc << 10;
  for (int s = tid; s < 4096; s += 256) {      // 4096 short4 slots
    int rowb = s >> 8;                         // 0..15 (rows 8..15 stay zero)
    int k4 = (s & 255) << 2;
    short4 v4 = {0, 0, 0, 0};
    if (rowb < 8) {
      float4 hv = *(const float4*)(h1 + ((size_t)rowb << 17) + kbase + k4);
      int c = k4 & 31;
      float4 scv = *(const float4*)(s_sc + c);
      float4 shv = *(const float4*)(s_sc + 32 + c);
      v4.x = (short)f2bf(fmaxf(hv.x * scv.x + shv.x, 0.f));
      v4.y = (short)f2bf(fmaxf(hv.y * scv.y + shv.y, 0.f));
      v4.z = (short)f2bf(fmaxf(hv.z * scv.z + shv.z, 0.f));
      v4.w = (short)f2bf(fmaxf(hv.w * scv.w + shv.w, 0.f));
    }
    int byte = ((rowb << 11) + (k4 << 1)) ^ ((rowb & 7) << 4);  // G4 swizzle
    *(short4*)((char*)als + byte) = v4;
  }
  __syncthreads();
  int lane = tid & 63, wave = tid >> 6;
  int l16 = lane & 15, quad = lane >> 4;
  int p = wave >> 1, khalf = wave & 1;         // 2 out-groups x 2 K-halves
  int o = og * 32 + p * 16 + l16;
  const float* wr = fc1w + (size_t)o * 131072 + kbase + (khalf << 9) + quad * 8;
  int abase = (l16 << 11) + (khalf << 10) + (quad << 4);
  int axor = (l16 & 7) << 4;
  f32x4 acc = {0.f, 0.f, 0.f, 0.f};
#pragma unroll 4
  for (int kk = 0; kk < 16; kk++) {
    const float* wp = wr + kk * 32;
    s16x8 bfr = cvt8v(*(const float4*)wp, *(const float4*)(wp + 4));
    s16x8 afr = *(const s16x8*)((const char*)als + ((abase + (kk << 6)) ^ axor));
    acc = __builtin_amdgcn_mfma_f32_16x16x32_bf16(afr, bfr, acc, 0, 0, 0);
  }
  __syncthreads();                             // als dead -> reuse for reduction
  float* red = (float*)smem;                   // [p][batch 8][out 16]
  if (khalf == 1 && quad < 2) {
#pragma unroll
    for (int i = 0; i < 4; i++)
      red[(p * 8 + quad * 4 + i) * 16 + l16] = acc[i];
  }
  __syncthreads();
  if (khalf == 0 && quad < 2) {                // D rows 0..7 = batches (m89 layout)
#pragma unroll
    for (int i = 0; i < 4; i++)
      atomicAdd(&fc1acc[(quad * 4 + i) * 256 + o],
                acc[i] + red[(p * 8 + quad * 4 + i) * 16 + l16]);
  }
}

// ---- K6: fc2
__global__ void fc2_kernel(const float* __restrict__ fc1acc,
                           const float* __restrict__ fc2w,
                           const float* __restrict__ fc2b,
                           float* __restrict__ out) {
  int t = blockIdx.x * blockDim.x + threadIdx.x;
  if (t < 424) fc2_elem(t, fc1acc, fc2w, fc2b, out);
}

// ---------------------------------------------------------------- launch
extern "C" void kernel_launch(void* const* d_in, const int* in_sizes, int n_in,
                              void* d_out, int out_size, void* d_ws, size_t ws_size,
                              hipStream_t stream) {
  float* out = (float*)d_out;
  int bad = 0;
  if (n_in != 25) bad = 2;
  else if (in_sizes[0] != 4194304) bad = 3;
  else if (in_sizes[2] != 65536) bad = 4;
  else if (in_sizes[21] != 33554432) bad = 5;
  else if (out_size != 424) bad = 6;
  else if (ws_size < 13509120) bad = 1;
  if (bad) {
    poison_kernel<<<2, 256, 0, stream>>>(out, out_size, (float)bad * 1.0e6f);
    return;
  }

  const float* x      = (const float*)d_in[0];
  const float* pseudo = (const float*)d_in[1];
  const int*   Lidx   = (const int*)d_in[2];
  const float* edge_w = (const float*)d_in[3];
  const float* edge_b = (const float*)d_in[4];
  const float* mu0    = (const float*)d_in[5];
  const float* sg0    = (const float*)d_in[6];
  const float* mu1    = (const float*)d_in[7];
  const float* sg1    = (const float*)d_in[8];
  const float* l1w0   = (const float*)d_in[9];
  const float* l1b0   = (const float*)d_in[10];
  const float* l2w0   = (const float*)d_in[11];
  const float* l2b0   = (const float*)d_in[12];
  const float* l1w1   = (const float*)d_in[13];
  const float* l1b1   = (const float*)d_in[14];
  const float* l2w1   = (const float*)d_in[15];
  const float* l2b1   = (const float*)d_in[16];
  const float* bng0   = (const float*)d_in[17];
  const float* bnb0   = (const float*)d_in[18];
  const float* bng1   = (const float*)d_in[19];
  const float* bnb1   = (const float*)d_in[20];
  const float* fc1w   = (const float*)d_in[21];
  const float* fc1b   = (const float*)d_in[22];
  const float* fc2w   = (const float*)d_in[23];
  const float* fc2b   = (const float*)d_in[24];

  char* Wp = (char*)d_ws;
  int*   colb   = (int*)  (Wp + 0);          // 65536 i32
  float* we0    = (float*)(Wp + 262144);     // 65536 f32
  float* we1    = (float*)(Wp + 524288);     // 65536 f32
  float* G      = (float*)(Wp + 786432);     // 32768 x 64 f32 (8 MB)
  float* h0     = (float*)(Wp + 9175040);    // 32768 x 32 f32 (4 MB); h1 aliases
  float* bn     = (float*)(Wp + 13369344);   // 4 x (32ch x 256 slots) f32
  float* fc1acc = (float*)(Wp + 13500928);   // 8x256 f32

  k1_kernel<<<664, 256, 0, stream>>>(x, l1w0, l2w0, G, pseudo, Lidx,
                                     edge_w, edge_b, mu0, sg0, mu1, sg1,
                                     we0, we1, colb, fc1acc, fc1b, bn);
  conv_kernel<<<4096, 256, 0, stream>>>(G, we0, colb, l1b0, l2b0,
                                        h0, bn, bn + 8192);
  proj1bn_kernel<<<512, 256, 0, stream>>>(h0, bn, bn + 8192, bng0, bnb0,
                                          l1w1, l2w1, G);
  conv_pf_kernel<<<4096, 256, 0, stream>>>(G, we1, colb, l1b1, l2b1,
                                           h0, bn + 16384, bn + 24576, fc1w);
  fc1bn_kernel<<<1024, 256, 0, stream>>>(h0, bn + 16384, bn + 24576,
                                         bng1, bnb1, fc1w, fc1acc);
  fc2_kernel<<<2, 256, 0, stream>>>(fc1acc, fc2w, fc2b, out);
}

// Round 6
// 337.871 us; speedup vs baseline: 3.9788x; 1.0103x over previous
//
#include <hip/hip_runtime.h>

#define B_ 8
#define M_ 4096
#define W_ 128
#define C_ 32
#define NN_ 16

typedef short s16x8 __attribute__((ext_vector_type(8)));
typedef float f32x4 __attribute__((ext_vector_type(4)));

static __device__ __forceinline__ unsigned short f2bf(float f) {
  unsigned u = __builtin_bit_cast(unsigned, f);
  u = u + 0x7FFFu + ((u >> 16) & 1u);   // RNE
  return (unsigned short)(u >> 16);
}
static __device__ __forceinline__ s16x8 cvt8v(float4 a, float4 b) {
  s16x8 r;
  r[0] = (short)f2bf(a.x); r[1] = (short)f2bf(a.y);
  r[2] = (short)f2bf(a.z); r[3] = (short)f2bf(a.w);
  r[4] = (short)f2bf(b.x); r[5] = (short)f2bf(b.y);
  r[6] = (short)f2bf(b.z); r[7] = (short)f2bf(b.w);
  return r;
}
static __device__ __forceinline__ float safeexp(float a) {
  return expf(fminf(a, 87.f));
}

// ---------------------------------------------------------------- poison (diagnostic sentinel)
__global__ void poison_kernel(float* __restrict__ out, int n, float val) {
  int t = blockIdx.x * blockDim.x + threadIdx.x;
  if (t < n) out[t] = val;
}

// ================================================================ device bodies (all proven)

// ---- attention row
static __device__ void attn_row(
    int m, const float* __restrict__ pseudo, const int* __restrict__ Lidx,
    const float* __restrict__ edge_w, const float* __restrict__ edge_b,
    const float* __restrict__ mu0, const float* __restrict__ sg0,
    const float* __restrict__ mu1, const float* __restrict__ sg1,
    float* __restrict__ we0, float* __restrict__ we1, int* __restrict__ colb) {
  float w0[NN_], w1[NN_];
  int col[NN_];
#pragma unroll
  for (int n = 0; n < NN_; n++) {
    int e = m * NN_ + n;
    float p0 = pseudo[e * 2], p1 = pseudo[e * 2 + 1];
    float emb[5];
#pragma unroll
    for (int d = 0; d < 5; d++)
      emb[d] = p0 * edge_w[d * 2] + p1 * edge_w[d * 2 + 1] + edge_b[d];
    float a0 = 0.f, a1 = 0.f;
#pragma unroll
    for (int j = 0; j < 4; j++) {
      float qa = 0.f, qb = 0.f;
#pragma unroll
      for (int d = 0; d < 5; d++) {
        float u0 = emb[d] - mu0[j * 5 + d];
        qa += u0 * u0 * sg0[j * 5 + d];
        float u1 = emb[d] - mu1[j * 5 + d];
        qb += u1 * u1 * sg1[j * 5 + d];
      }
      a0 += safeexp(-0.5f * qa);
      a1 += safeexp(-0.5f * qb);
    }
    w0[n] = a0; w1[n] = a1;
    col[n] = Lidx[e] % M_;
  }
  float mx0 = w0[0], mx1 = w1[0];
#pragma unroll
  for (int n = 1; n < NN_; n++) { mx0 = fmaxf(mx0, w0[n]); mx1 = fmaxf(mx1, w1[n]); }
  float s0 = 0.f, s1 = 0.f;
#pragma unroll
  for (int n = 0; n < NN_; n++) {
    w0[n] = safeexp(w0[n] - mx0); s0 += w0[n];
    w1[n] = safeexp(w1[n] - mx1); s1 += w1[n];
  }
  float r0 = 1.f / s0, r1 = 1.f / s1;
#pragma unroll
  for (int n = 0; n < NN_; n++) {
    bool last = true;                       // numpy fancy-set: last duplicate wins
#pragma unroll
    for (int n2 = n + 1; n2 < NN_; n2++)
      if (col[n2] == col[n]) last = false;
    int e = m * NN_ + n;
    we0[e] = last ? w0[n] * r0 : 0.f;
    we1[e] = last ? w1[n] * r1 : 0.f;
    colb[e] = col[n];
  }
}

// ---- proj0 tile: G[r][0:32]=x@l1w0.T, G[r][32:64]=x@l2w0.T
static __device__ void proj0_tile(
    int blk, int tid, const float* __restrict__ x, const float* __restrict__ l1w0,
    const float* __restrict__ l2w0, float* __restrict__ G) {
  int lane = tid & 63, wave = tid >> 6;
  int l16 = lane & 15, quad = lane >> 4;
  int tile = blk * 4 + wave;                   // 2048 tiles of 16 rows
  f32x4 acc[4];
#pragma unroll
  for (int ct = 0; ct < 4; ct++) acc[ct] = (f32x4){0.f, 0.f, 0.f, 0.f};
  int row = tile * 16 + l16;
  const float* xr = x + (size_t)row * 128 + quad * 8;
#pragma unroll
  for (int kit = 0; kit < 4; kit++) {
    const float* ap = xr + kit * 32;
    s16x8 a = cvt8v(*(const float4*)ap, *(const float4*)(ap + 4));
#pragma unroll
    for (int ct = 0; ct < 4; ct++) {
      int out = ct * 16 + l16;
      const float* src = (out < 32 ? l1w0 + out * 128 : l2w0 + (out - 32) * 128)
                         + kit * 32 + quad * 8;
      s16x8 bf = cvt8v(*(const float4*)src, *(const float4*)(src + 4));
      acc[ct] = __builtin_amdgcn_mfma_f32_16x16x32_bf16(a, bf, acc[ct], 0, 0, 0);
    }
  }
  int rbase = tile * 16 + quad * 4;            // C/D: col=lane&15, row=quad*4+i (m89)
#pragma unroll
  for (int ct = 0; ct < 4; ct++)
#pragma unroll
    for (int i = 0; i < 4; i++)
      G[(size_t)(rbase + i) * 64 + ct * 16 + l16] = acc[ct][i];
}

// ---- conv block: h = L.G1 + G2 + b1 + b2; BN partials. smem: 1280 B.
// cb = data block (XCD-swizzled by caller so batch(cb)==XCD); slot = raw bid&255.
static __device__ void conv_block(
    int cb, int slot, int tid, char* smem,
    const float* __restrict__ G, const float* __restrict__ we,
    const int* __restrict__ colb, const float* __restrict__ b1c,
    const float* __restrict__ b2c, float* __restrict__ h,
    float* __restrict__ bns, float* __restrict__ bnq) {
  float (*s_we)[16] = (float(*)[16])smem;
  int   (*s_cn)[16] = (int(*)[16])(smem + 512);
  float* s_s = (float*)(smem + 1024);
  float* s_q = (float*)(smem + 1152);
  if (tid < 128) {
    int row = tid >> 4, nn = tid & 15;
    int m = (cb * 8 + row) & 4095;             // attn arrays are per-m
    s_we[row][nn] = we[m * 16 + nn];
    s_cn[row][nn] = colb[m * 16 + nn];
  } else if (tid < 160) {
    s_s[tid - 128] = 0.f;
    s_q[tid - 128] = 0.f;
  }
  __syncthreads();
  int row = tid >> 5, c = tid & 31;
  int r = cb * 8 + row;
  int b = r >> 12;
  const float* Gb = G + ((size_t)b << 18);     // b*4096*64
  float g2 = G[(size_t)r * 64 + 32 + c];       // issue early (overlaps gathers)
  float acc = 0.f;
#pragma unroll
  for (int nn = 0; nn < NN_; nn++)             // 16 independent gathers in flight
    acc += s_we[row][nn] * Gb[s_cn[row][nn] * 64 + c];
  float hv = acc + g2 + b1c[c] + b2c[c];
  h[(size_t)r * 32 + c] = hv;
  atomicAdd(&s_s[c], hv);
  atomicAdd(&s_q[c], hv * hv);
  __syncthreads();
  if (tid < 32) {
    atomicAdd(&bns[tid * 256 + slot], s_s[tid]);
    atomicAdd(&bnq[tid * 256 + slot], s_q[tid]);
  }
}

// ---- BN finalize, computed locally per block into LDS s_sc[64] (scale|shift).
static __device__ void bnfin_local(
    int tid, char* smem, const float* __restrict__ bns, const float* __restrict__ bnq,
    const float* __restrict__ g, const float* __restrict__ bb,
    float* __restrict__ s_sc) {
  float (*red)[8][32] = (float(*)[8][32])smem;
  int c = tid & 31, part = tid >> 5;
  float s = 0.f, q = 0.f;
#pragma unroll 8
  for (int i = 0; i < 32; i++) {
    s += bns[c * 256 + part * 32 + i];
    q += bnq[c * 256 + part * 32 + i];
  }
  red[0][part][c] = s;
  red[1][part][c] = q;
  __syncthreads();
  if (tid < 32) {
    float S = 0.f, Q = 0.f;
#pragma unroll
    for (int p = 0; p < 8; p++) { S += red[0][p][tid]; Q += red[1][p][tid]; }
    float mean = S * (1.f / 32768.f);
    float var = fmaxf(Q * (1.f / 32768.f) - mean * mean, 0.f);
    float sc = g[tid] * rsqrtf(var + 1e-5f);
    s_sc[tid] = sc;
    s_sc[32 + tid] = bb[tid] - mean * sc;
  }
  __syncthreads();
}

// ---- proj1 tile (K=32): a=relu(bn0(h0)); G=[a@l1w1.T | a@l2w1.T]; sc0 in LDS
static __device__ void proj1_tile(
    int blk, int tid, const float* __restrict__ h0, const float* __restrict__ sc0,
    const float* __restrict__ l1w1, const float* __restrict__ l2w1,
    float* __restrict__ G) {
  int lane = tid & 63, wave = tid >> 6;
  int l16 = lane & 15, quad = lane >> 4;
  int tile = blk * 4 + wave;
  int row = tile * 16 + l16;
  const float* hr = h0 + (size_t)row * 32 + quad * 8;
  float4 hv0 = *(const float4*)hr;
  float4 hv1 = *(const float4*)(hr + 4);
  float av[8] = {hv0.x, hv0.y, hv0.z, hv0.w, hv1.x, hv1.y, hv1.z, hv1.w};
  s16x8 a;
#pragma unroll
  for (int j = 0; j < 8; j++) {
    float scv = sc0[quad * 8 + j];
    float shv = sc0[32 + quad * 8 + j];
    a[j] = (short)f2bf(fmaxf(av[j] * scv + shv, 0.f));
  }
  f32x4 acc[4];
#pragma unroll
  for (int ct = 0; ct < 4; ct++) {
    int out = ct * 16 + l16;
    const float* src = (out < 32 ? l1w1 + out * 32 : l2w1 + (out - 32) * 32) + quad * 8;
    s16x8 bf = cvt8v(*(const float4*)src, *(const float4*)(src + 4));
    f32x4 z = {0.f, 0.f, 0.f, 0.f};
    acc[ct] = __builtin_amdgcn_mfma_f32_16x16x32_bf16(a, bf, z, 0, 0, 0);
  }
  int rbase = tile * 16 + quad * 4;
#pragma unroll
  for (int ct = 0; ct < 4; ct++)
#pragma unroll
    for (int i = 0; i < 4; i++)
      G[(size_t)(rbase + i) * 64 + ct * 16 + l16] = acc[ct][i];
}

// ---- fc2 element
static __device__ void fc2_elem(
    int t, const float* __restrict__ fc1acc, const float* __restrict__ fc2w,
    const float* __restrict__ fc2b, float* __restrict__ out) {
  int b = t / 53, j = t - b * 53;
  float s = fc2b[j];
  const float* fa = fc1acc + b * 256;
  const float* wr = fc2w + j * 256;
#pragma unroll 8
  for (int o = 0; o < 256; o++) s += fmaxf(fa[o], 0.f) * wr[o];
  out[t] = s;
}

// ================================================================ kernels (6 launches)

// ---- K1: proj0 (0..511) | attn (512..527) | init fc1acc+bn (528..663)
__global__ __launch_bounds__(256) void k1_kernel(
    const float* __restrict__ x, const float* __restrict__ l1w0,
    const float* __restrict__ l2w0, float* __restrict__ G,
    const float* __restrict__ pseudo, const int* __restrict__ Lidx,
    const float* __restrict__ edge_w, const float* __restrict__ edge_b,
    const float* __restrict__ mu0, const float* __restrict__ sg0,
    const float* __restrict__ mu1, const float* __restrict__ sg1,
    float* __restrict__ we0, float* __restrict__ we1, int* __restrict__ colb,
    float* __restrict__ fc1acc, const float* __restrict__ fc1b,
    float* __restrict__ bn) {
  int bid = blockIdx.x, tid = threadIdx.x;
  if (bid < 512) {
    proj0_tile(bid, tid, x, l1w0, l2w0, G);
  } else if (bid < 528) {
    attn_row((bid - 512) * 256 + tid, pseudo, Lidx, edge_w, edge_b,
             mu0, sg0, mu1, sg1, we0, we1, colb);
  } else {
    int g = (bid - 528) * 256 + tid;           // 0..34815
    if (g < 2048) fc1acc[g] = fc1b[g & 255];
    else bn[g - 2048] = 0.f;
  }
}

// ---- K2: conv0, XCD-swizzled: cb = (bid&7)*512 + bid>>3 puts all 512 blocks
// of batch b on XCD b (XCD = bid%8 round-robin, m09) -> each XCD's 4MB L2
// caches only its own 1MB G-slice -> gathers become L2 hits instead of
// L3/HBM-latency misses. Bijective (4096 = 8*512, ERRATA #11).
__global__ __launch_bounds__(256) void conv_kernel(
    const float* __restrict__ G,
    const float* __restrict__ we, const int* __restrict__ colb,
    const float* __restrict__ b1c, const float* __restrict__ b2c,
    float* __restrict__ h, float* __restrict__ bns, float* __restrict__ bnq) {
  __shared__ char smem[1280];
  int bid = blockIdx.x;
  int cb = ((bid & 7) << 9) | (bid >> 3);
  conv_block(cb, bid & 255, threadIdx.x, smem, G, we, colb, b1c, b2c, h, bns, bnq);
}

// ---- K3: bnfin0 (local) + proj1
__global__ __launch_bounds__(256) void proj1bn_kernel(
    const float* __restrict__ h0,
    const float* __restrict__ bns, const float* __restrict__ bnq,
    const float* __restrict__ g0, const float* __restrict__ b0,
    const float* __restrict__ l1w1, const float* __restrict__ l2w1,
    float* __restrict__ G) {
  __shared__ char smem[2048];
  __shared__ __align__(16) float s_sc[64];
  bnfin_local(threadIdx.x, smem, bns, bnq, g0, b0, s_sc);
  proj1_tile(blockIdx.x, threadIdx.x, h0, s_sc, l1w1, l2w1, G);
}

// ---- K4: conv1 (XCD-swizzled) + fc1w L3-prefetch tail (32 KB/block x 4096).
__global__ __launch_bounds__(256) void conv_pf_kernel(
    const float* __restrict__ G,
    const float* __restrict__ we, const int* __restrict__ colb,
    const float* __restrict__ b1c, const float* __restrict__ b2c,
    float* __restrict__ h, float* __restrict__ bns, float* __restrict__ bnq,
    const float* __restrict__ fc1w) {
  __shared__ char smem[1280];
  int bid = blockIdx.x;
  int cb = ((bid & 7) << 9) | (bid >> 3);
  conv_block(cb, bid & 255, threadIdx.x, smem, G, we, colb, b1c, b2c, h, bns, bnq);
  const float4* pw = (const float4*)fc1w;
  int base = bid * 2048 + threadIdx.x;
  float a = 0.f;
#pragma unroll
  for (int j = 0; j < 8; j++) {                // dead-read kept live (rule #17)
    float4 v = pw[base + j * 256];
    a += v.x + v.y + v.z + v.w;
  }
  asm volatile("" :: "v"(a));
}

// ---- K5: bnfin1 (local) + fc1 MFMA. 1024 blocks = (kc 0..127) x (og 0..7).
__global__ __launch_bounds__(256) void fc1bn_kernel(
    const float* __restrict__ h1,
    const float* __restrict__ bns, const float* __restrict__ bnq,
    const float* __restrict__ g1, const float* __restrict__ b1,
    const float* __restrict__ fc1w, float* __restrict__ fc1acc) {
  __shared__ char smem[32768];
  __shared__ __align__(16) float s_sc[64];
  int tid = threadIdx.x;
  bnfin_local(tid, smem, bns, bnq, g1, b1, s_sc);
  short* als = (short*)smem;                   // bf16 [16][1024], row stride 2048 B
  int kc = blockIdx.x >> 3;                    // 0..127: k-chunk of 1024
  int og = blockIdx.x & 7;                     // 0..7: outputs og*32..+31
  size_t kbase = (size_t)kc << 10;
  for (int s = tid; s < 4096; s += 256) {      // 4096 short4 slots
    int rowb = s >> 8;                         // 0..15 (rows 8..15 stay zero)
    int k4 = (s & 255) << 2;
    short4 v4 = {0, 0, 0, 0};
    if (rowb < 8) {
      float4 hv = *(const float4*)(h1 + ((size_t)rowb << 17) + kbase + k4);
      int c = k4 & 31;
      float4 scv = *(const float4*)(s_sc + c);
      float4 shv = *(const float4*)(s_sc + 32 + c);
      v4.x = (short)f2bf(fmaxf(hv.x * scv.x + shv.x, 0.f));
      v4.y = (short)f2bf(fmaxf(hv.y * scv.y + shv.y, 0.f));
      v4.z = (short)f2bf(fmaxf(hv.z * scv.z + shv.z, 0.f));
      v4.w = (short)f2bf(fmaxf(hv.w * scv.w + shv.w, 0.f));
    }
    int byte = ((rowb << 11) + (k4 << 1)) ^ ((rowb & 7) << 4);  // G4 swizzle
    *(short4*)((char*)als + byte) = v4;
  }
  __syncthreads();
  int lane = tid & 63, wave = tid >> 6;
  int l16 = lane & 15, quad = lane >> 4;
  int p = wave >> 1, khalf = wave & 1;         // 2 out-groups x 2 K-halves
  int o = og * 32 + p * 16 + l16;
  const float* wr = fc1w + (size_t)o * 131072 + kbase + (khalf << 9) + quad * 8;
  int abase = (l16 << 11) + (khalf << 10) + (quad << 4);
  int axor = (l16 & 7) << 4;
  f32x4 acc = {0.f, 0.f, 0.f, 0.f};
#pragma unroll 4
  for (int kk = 0; kk < 16; kk++) {
    const float* wp = wr + kk * 32;
    s16x8 bfr = cvt8v(*(const float4*)wp, *(const float4*)(wp + 4));
    s16x8 afr = *(const s16x8*)((const char*)als + ((abase + (kk << 6)) ^ axor));
    acc = __builtin_amdgcn_mfma_f32_16x16x32_bf16(afr, bfr, acc, 0, 0, 0);
  }
  __syncthreads();                             // als dead -> reuse for reduction
  float* red = (float*)smem;                   // [p][batch 8][out 16]
  if (khalf == 1 && quad < 2) {
#pragma unroll
    for (int i = 0; i < 4; i++)
      red[(p * 8 + quad * 4 + i) * 16 + l16] = acc[i];
  }
  __syncthreads();
  if (khalf == 0 && quad < 2) {                // D rows 0..7 = batches (m89 layout)
#pragma unroll
    for (int i = 0; i < 4; i++)
      atomicAdd(&fc1acc[(quad * 4 + i) * 256 + o],
                acc[i] + red[(p * 8 + quad * 4 + i) * 16 + l16]);
  }
}

// ---- K6: fc2
__global__ void fc2_kernel(const float* __restrict__ fc1acc,
                           const float* __restrict__ fc2w,
                           const float* __restrict__ fc2b,
                           float* __restrict__ out) {
  int t = blockIdx.x * blockDim.x + threadIdx.x;
  if (t < 424) fc2_elem(t, fc1acc, fc2w, fc2b, out);
}

// ---------------------------------------------------------------- launch
extern "C" void kernel_launch(void* const* d_in, const int* in_sizes, int n_in,
                              void* d_out, int out_size, void* d_ws, size_t ws_size,
                              hipStream_t stream) {
  float* out = (float*)d_out;
  int bad = 0;
  if (n_in != 25) bad = 2;
  else if (in_sizes[0] != 4194304) bad = 3;
  else if (in_sizes[2] != 65536) bad = 4;
  else if (in_sizes[21] != 33554432) bad = 5;
  else if (out_size != 424) bad = 6;
  else if (ws_size < 13509120) bad = 1;
  if (bad) {
    poison_kernel<<<2, 256, 0, stream>>>(out, out_size, (float)bad * 1.0e6f);
    return;
  }

  const float* x      = (const float*)d_in[0];
  const float* pseudo = (const float*)d_in[1];
  const int*   Lidx   = (const int*)d_in[2];
  const float* edge_w = (const float*)d_in[3];
  const float* edge_b = (const float*)d_in[4];
  const float* mu0    = (const float*)d_in[5];
  const float* sg0    = (const float*)d_in[6];
  const float* mu1    = (const float*)d_in[7];
  const float* sg1    = (const float*)d_in[8];
  const float* l1w0   = (const float*)d_in[9];
  const float* l1b0   = (const float*)d_in[10];
  const float* l2w0   = (const float*)d_in[11];
  const float* l2b0   = (const float*)d_in[12];
  const float* l1w1   = (const float*)d_in[13];
  const float* l1b1   = (const float*)d_in[14];
  const float* l2w1   = (const float*)d_in[15];
  const float* l2b1   = (const float*)d_in[16];
  const float* bng0   = (const float*)d_in[17];
  const float* bnb0   = (const float*)d_in[18];
  const float* bng1   = (const float*)d_in[19];
  const float* bnb1   = (const float*)d_in[20];
  const float* fc1w   = (const float*)d_in[21];
  const float* fc1b   = (const float*)d_in[22];
  const float* fc2w   = (const float*)d_in[23];
  const float* fc2b   = (const float*)d_in[24];

  char* Wp = (char*)d_ws;
  int*   colb   = (int*)  (Wp + 0);          // 65536 i32
  float* we0    = (float*)(Wp + 262144);     // 65536 f32
  float* we1    = (float*)(Wp + 524288);     // 65536 f32
  float* G      = (float*)(Wp + 786432);     // 32768 x 64 f32 (8 MB)
  float* h0     = (float*)(Wp + 9175040);    // 32768 x 32 f32 (4 MB); h1 aliases
  float* bn     = (float*)(Wp + 13369344);   // 4 x (32ch x 256 slots) f32
  float* fc1acc = (float*)(Wp + 13500928);   // 8x256 f32

  k1_kernel<<<664, 256, 0, stream>>>(x, l1w0, l2w0, G, pseudo, Lidx,
                                     edge_w, edge_b, mu0, sg0, mu1, sg1,
                                     we0, we1, colb, fc1acc, fc1b, bn);
  conv_kernel<<<4096, 256, 0, stream>>>(G, we0, colb, l1b0, l2b0,
                                        h0, bn, bn + 8192);
  proj1bn_kernel<<<512, 256, 0, stream>>>(h0, bn, bn + 8192, bng0, bnb0,
                                          l1w1, l2w1, G);
  conv_pf_kernel<<<4096, 256, 0, stream>>>(G, we1, colb, l1b1, l2b1,
                                           h0, bn + 16384, bn + 24576, fc1w);
  fc1bn_kernel<<<1024, 256, 0, stream>>>(h0, bn + 16384, bn + 24576,
                                         bng1, bnb1, fc1w, fc1acc);
  fc2_kernel<<<2, 256, 0, stream>>>(fc1acc, fc2w, fc2b, out);
}